// Round 8
// baseline (15101.671 us; speedup 1.0000x reference)
//
#include <hip/hip_runtime.h>
#include <math.h>

#define VOCAB  32000
#define EMB    256
#define HID    512
#define MAXLEN 512
#define BATCH  128
#define NCLASS 2

#define NB_J    8    // column groups (64 cols each)
#define NB_B    32   // batch groups (4 rows each)
#define ROWS_PB 4
#define COLS_PB 64

// ---------------------------------------------------------------------------
// Kernel A: embW[v][j] = b_h[j] + sum_e emb[v][e] * W_ih[e][j]
// (unchanged — ~70 us)
// ---------------------------------------------------------------------------
__global__ __launch_bounds__(256, 1) void embw_kernel(
    const float* __restrict__ emb, const float* __restrict__ W_ih,
    const float* __restrict__ b_h, float* __restrict__ embW)
{
    __shared__ __align__(16) float aT[EMB][64];
    __shared__ __align__(16) float wS[32][HID];

    const int t    = threadIdx.x;
    const int row0 = blockIdx.x * 64;

    {
        const int row   = t >> 2;
        const int elane = t & 3;
        for (int i = 0; i < 16; ++i) {
            const int e = elane * 4 + i * 16;
            const float4 v = *reinterpret_cast<const float4*>(
                &emb[(size_t)(row0 + row) * EMB + e]);
            aT[e + 0][row] = v.x;
            aT[e + 1][row] = v.y;
            aT[e + 2][row] = v.z;
            aT[e + 3][row] = v.w;
        }
    }

    const int rg = t >> 5;
    const int cg = t & 31;

    float acc[8][16];
    #pragma unroll
    for (int r = 0; r < 8; ++r)
        #pragma unroll
        for (int c = 0; c < 16; ++c) acc[r][c] = 0.f;

    for (int ec = 0; ec < 8; ++ec) {
        __syncthreads();
        {
            const int j4  = (t & 127) * 4;
            const int keb = (t >> 7);
            #pragma unroll
            for (int i = 0; i < 16; ++i) {
                const int ke = keb + i * 2;
                const float4 v = *reinterpret_cast<const float4*>(
                    &W_ih[(size_t)(ec * 32 + ke) * HID + j4]);
                *reinterpret_cast<float4*>(&wS[ke][j4]) = v;
            }
        }
        __syncthreads();

        for (int ke = 0; ke < 32; ++ke) {
            float a8[8];
            *(float4*)&a8[0] = *(const float4*)&aT[ec * 32 + ke][rg * 8];
            *(float4*)&a8[4] = *(const float4*)&aT[ec * 32 + ke][rg * 8 + 4];
            float w16[16];
            #pragma unroll
            for (int q = 0; q < 4; ++q)
                *(float4*)&w16[q * 4] =
                    *(const float4*)&wS[ke][cg * 16 + q * 4];
            #pragma unroll
            for (int r = 0; r < 8; ++r)
                #pragma unroll
                for (int c = 0; c < 16; ++c)
                    acc[r][c] = fmaf(a8[r], w16[c], acc[r][c]);
        }
    }

    float bh[16];
    #pragma unroll
    for (int q = 0; q < 4; ++q)
        *(float4*)&bh[q * 4] = *(const float4*)&b_h[cg * 16 + q * 4];
    #pragma unroll
    for (int r = 0; r < 8; ++r) {
        const size_t orow = (size_t)(row0 + rg * 8 + r) * HID + cg * 16;
        #pragma unroll
        for (int q = 0; q < 4; ++q) {
            float4 v;
            v.x = acc[r][q * 4 + 0] + bh[q * 4 + 0];
            v.y = acc[r][q * 4 + 1] + bh[q * 4 + 1];
            v.z = acc[r][q * 4 + 2] + bh[q * 4 + 2];
            v.w = acc[r][q * 4 + 3] + bh[q * 4 + 3];
            *reinterpret_cast<float4*>(&embW[orow + q * 4]) = v;
        }
    }
}

// ---------------------------------------------------------------------------
// Kernel B: sequential RNN — W in LDS (b128 economy) + wave-flag exchange.
// 256 blocks x 512 threads (1/CU; 147KB LDS forces 1/CU => co-resident).
// Block (bgrp=bid&31, jgrp=bid>>5): rows r0..r0+3, cols j0..j0+63.
// W slice [512][64] fp32 = 128KB LDS (R6/R7 lesson: compiler refuses VGPR
//   residency — spills to scratch; LDS is the reliable home. R4 lesson:
//   per-lane b32 W reads were LDS-instr-bound; b128 reads are 8x fewer and
//   data-limited ~8cy).
// k-loop identity: wave w = k-octant; lane: cq=l&15 (cols 4cq..4cq+3),
//   ks=l>>4 (16 k's). h read b128, 16-lane same-address broadcast (free).
// 4-way ks-split reduced in-register (__shfl_xor 16/32 butterfly) ->
//   pb only [8][4][64] = 8KB.
// Exchange: per-(bgrp,jgrp) MONOTONE flag (no reset). Publisher: relaxed
//   agent stores -> __syncthreads (vmcnt drain) -> t0 release-store ts+1.
//   Consumer: wave w spins acquire on sibling w's flag >= ts, loads that
//   piece. 8 spin+load chains in parallel (vs R4's serial central counter).
// ---------------------------------------------------------------------------
__global__ __launch_bounds__(512, 1) void rnn_kernel(
    const int* __restrict__ inputs, const float* __restrict__ embW,
    const float* __restrict__ W_hh, float* hA, float* hB,
    int* flags)
{
    __shared__ __align__(16) float Wl[HID][COLS_PB];       // 128 KB
    __shared__ __align__(16) float hs[ROWS_PB][HID];       // 8 KB
    __shared__ __align__(16) float pb[NB_J][ROWS_PB][COLS_PB]; // 8 KB

    const int t    = threadIdx.x;
    const int w    = t >> 6;          // wave 0..7
    const int l    = t & 63;          // lane
    const int bid  = blockIdx.x;
    const int bgrp = bid & 31;
    const int jgrp = bid >> 5;
    const int j0   = jgrp * COLS_PB;
    const int r0   = bgrp * ROWS_PB;
    const int cq4  = (l & 15) * 4;    // col quad (k-loop identity)
    const int koff = w * 64 + (l >> 4) * 16;   // this thread's 16-k window
    const int rc   = t >> 6;          // combine row (valid for t<256)

    // ---- stage W slice once: wave w covers k rows w*64..w*64+63 ----
    {
        const int ksub = l >> 4;
        #pragma unroll
        for (int i = 0; i < 16; ++i) {
            const int k = w * 64 + ksub * 16 + i;
            *(float4*)&Wl[k][cq4] =
                *(const float4*)&W_hh[(size_t)k * HID + j0 + cq4];
        }
    }

    for (int ts = 0; ts < MAXLEN; ++ts) {
        float* hc = (ts & 1) ? hB : hA;
        float* hn = (ts & 1) ? hA : hB;

        // ---- wait for sibling piece w, then stage it (parallel per wave) --
        if (ts > 0) {
            while (__hip_atomic_load(&flags[bgrp * NB_J + w],
                                     __ATOMIC_ACQUIRE,
                                     __HIP_MEMORY_SCOPE_AGENT) < ts) {
                __builtin_amdgcn_s_sleep(1);
            }
        }
        #pragma unroll
        for (int r = 0; r < ROWS_PB; ++r) {
            const float v = __hip_atomic_load(
                &hc[(size_t)(r0 + r) * HID + w * 64 + l],
                __ATOMIC_RELAXED, __HIP_MEMORY_SCOPE_AGENT);
            hs[r][w * 64 + l] = v;
        }

        // feedforward gather (combine threads; L3 latency hides under kloop)
        float ev = 0.f;
        if (t < 256) {
            const int tok = inputs[(r0 + rc) * MAXLEN + ts];
            ev = embW[(size_t)tok * HID + j0 + l];
        }
        __syncthreads();

        // ---- k-loop: 16 k's, 4 cols, 4 rows; W b128, h b128 broadcast ----
        float acc[ROWS_PB][4];
        #pragma unroll
        for (int r = 0; r < ROWS_PB; ++r)
            #pragma unroll
            for (int c = 0; c < 4; ++c) acc[r][c] = 0.f;

        #pragma unroll
        for (int i = 0; i < 4; ++i) {
            const int kk = koff + i * 4;
            const float4 w0 = *(const float4*)&Wl[kk + 0][cq4];
            const float4 w1 = *(const float4*)&Wl[kk + 1][cq4];
            const float4 w2 = *(const float4*)&Wl[kk + 2][cq4];
            const float4 w3 = *(const float4*)&Wl[kk + 3][cq4];
            #pragma unroll
            for (int r = 0; r < ROWS_PB; ++r) {
                const float4 h4 = *(const float4*)&hs[r][kk];
                acc[r][0] = fmaf(w0.x, h4.x, acc[r][0]);
                acc[r][1] = fmaf(w0.y, h4.x, acc[r][1]);
                acc[r][2] = fmaf(w0.z, h4.x, acc[r][2]);
                acc[r][3] = fmaf(w0.w, h4.x, acc[r][3]);
                acc[r][0] = fmaf(w1.x, h4.y, acc[r][0]);
                acc[r][1] = fmaf(w1.y, h4.y, acc[r][1]);
                acc[r][2] = fmaf(w1.z, h4.y, acc[r][2]);
                acc[r][3] = fmaf(w1.w, h4.y, acc[r][3]);
                acc[r][0] = fmaf(w2.x, h4.z, acc[r][0]);
                acc[r][1] = fmaf(w2.y, h4.z, acc[r][1]);
                acc[r][2] = fmaf(w2.z, h4.z, acc[r][2]);
                acc[r][3] = fmaf(w2.w, h4.z, acc[r][3]);
                acc[r][0] = fmaf(w3.x, h4.w, acc[r][0]);
                acc[r][1] = fmaf(w3.y, h4.w, acc[r][1]);
                acc[r][2] = fmaf(w3.z, h4.w, acc[r][2]);
                acc[r][3] = fmaf(w3.w, h4.w, acc[r][3]);
            }
        }

        // ---- reduce the 4-way ks split in-register (lanes l, l^16, l^32,
        //      l^48 hold partials of the same (row, col-quad)) ----
        #pragma unroll
        for (int r = 0; r < ROWS_PB; ++r)
            #pragma unroll
            for (int c = 0; c < 4; ++c) {
                float v = acc[r][c];
                v += __shfl_xor(v, 16);
                v += __shfl_xor(v, 32);
                acc[r][c] = v;
            }
        if (l < 16) {
            #pragma unroll
            for (int r = 0; r < ROWS_PB; ++r)
                *(float4*)&pb[w][r][l * 4] = make_float4(
                    acc[r][0], acc[r][1], acc[r][2], acc[r][3]);
        }
        __syncthreads();

        // ---- combine (t<256: row rc, col l), tanh, publish ----
        if (t < 256) {
            float s = ev;
            #pragma unroll
            for (int q = 0; q < NB_J; ++q) s += pb[q][rc][l];
            s = tanhf(s);
            __hip_atomic_store(&hn[(size_t)(r0 + rc) * HID + j0 + l], s,
                               __ATOMIC_RELAXED, __HIP_MEMORY_SCOPE_AGENT);
        }
        __syncthreads();   // vmcnt drain: all piece stores complete

        if (t == 0)
            __hip_atomic_store(&flags[bgrp * NB_J + jgrp], ts + 1,
                               __ATOMIC_RELEASE, __HIP_MEMORY_SCOPE_AGENT);
    }
    // final h in hA (MAXLEN even)
}

// ---------------------------------------------------------------------------
// Kernel C: logits = hA @ W_out + b_out, sigmoid. Tiny.
// ---------------------------------------------------------------------------
__global__ void head_kernel(const float* __restrict__ h_final,
                            const float* __restrict__ W_out,
                            const float* __restrict__ b_out,
                            float* __restrict__ out)
{
    const int t = threadIdx.x;
    const int b = t >> 1, c = t & 1;
    float acc = b_out[c];
    for (int k = 0; k < HID; ++k)
        acc = fmaf(h_final[(size_t)b * HID + k], W_out[k * NCLASS + c], acc);
    out[t] = 1.f / (1.f + expf(-acc));
}

// ---------------------------------------------------------------------------
extern "C" void kernel_launch(void* const* d_in, const int* in_sizes, int n_in,
                              void* d_out, int out_size, void* d_ws,
                              size_t ws_size, hipStream_t stream)
{
    const int*   inputs = (const int*)  d_in[0];
    const float* emb    = (const float*)d_in[1];
    const float* W_ih   = (const float*)d_in[2];
    const float* W_hh   = (const float*)d_in[3];
    const float* b_h    = (const float*)d_in[4];
    const float* W_out  = (const float*)d_in[5];
    const float* b_out  = (const float*)d_in[6];
    float* out = (float*)d_out;

    // ws layout: embW 64 MB | hA 256 KB | hB 256 KB | flags 1 KB
    float* embW  = (float*)d_ws;
    float* hA    = embW + (size_t)VOCAB * HID;
    float* hB    = hA + (size_t)BATCH * HID;
    int*   flags = (int*)(hB + (size_t)BATCH * HID);

    // per-launch re-init (graph-capture-safe, deterministic)
    hipMemsetAsync(hA, 0, (size_t)BATCH * HID * sizeof(float), stream);
    hipMemsetAsync(flags, 0, (size_t)NB_B * NB_J * sizeof(int), stream);

    embw_kernel<<<VOCAB / 64, 256, 0, stream>>>(emb, W_ih, b_h, embW);
    rnn_kernel<<<NB_B * NB_J, 512, 0, stream>>>(inputs, embW, W_hh,
                                                hA, hB, flags);
    head_kernel<<<1, 256, 0, stream>>>(hA, W_out, b_out, out);
}

// Round 9
// 4236.328 us; speedup vs baseline: 3.5648x; 3.5648x over previous
//
#include <hip/hip_runtime.h>
#include <math.h>

#define VOCAB  32000
#define EMB    256
#define HID    512
#define MAXLEN 512
#define BATCH  128
#define NCLASS 2

#define NB_J    8    // column groups (64 cols each)
#define NB_B    32   // batch groups (4 rows each)
#define ROWS_PB 4
#define COLS_PB 64

// ---------------------------------------------------------------------------
// Kernel A: embW[v][j] = b_h[j] + sum_e emb[v][e] * W_ih[e][j]
// (unchanged — ~70 us)
// ---------------------------------------------------------------------------
__global__ __launch_bounds__(256, 1) void embw_kernel(
    const float* __restrict__ emb, const float* __restrict__ W_ih,
    const float* __restrict__ b_h, float* __restrict__ embW)
{
    __shared__ __align__(16) float aT[EMB][64];
    __shared__ __align__(16) float wS[32][HID];

    const int t    = threadIdx.x;
    const int row0 = blockIdx.x * 64;

    {
        const int row   = t >> 2;
        const int elane = t & 3;
        for (int i = 0; i < 16; ++i) {
            const int e = elane * 4 + i * 16;
            const float4 v = *reinterpret_cast<const float4*>(
                &emb[(size_t)(row0 + row) * EMB + e]);
            aT[e + 0][row] = v.x;
            aT[e + 1][row] = v.y;
            aT[e + 2][row] = v.z;
            aT[e + 3][row] = v.w;
        }
    }

    const int rg = t >> 5;
    const int cg = t & 31;

    float acc[8][16];
    #pragma unroll
    for (int r = 0; r < 8; ++r)
        #pragma unroll
        for (int c = 0; c < 16; ++c) acc[r][c] = 0.f;

    for (int ec = 0; ec < 8; ++ec) {
        __syncthreads();
        {
            const int j4  = (t & 127) * 4;
            const int keb = (t >> 7);
            #pragma unroll
            for (int i = 0; i < 16; ++i) {
                const int ke = keb + i * 2;
                const float4 v = *reinterpret_cast<const float4*>(
                    &W_ih[(size_t)(ec * 32 + ke) * HID + j4]);
                *reinterpret_cast<float4*>(&wS[ke][j4]) = v;
            }
        }
        __syncthreads();

        for (int ke = 0; ke < 32; ++ke) {
            float a8[8];
            *(float4*)&a8[0] = *(const float4*)&aT[ec * 32 + ke][rg * 8];
            *(float4*)&a8[4] = *(const float4*)&aT[ec * 32 + ke][rg * 8 + 4];
            float w16[16];
            #pragma unroll
            for (int q = 0; q < 4; ++q)
                *(float4*)&w16[q * 4] =
                    *(const float4*)&wS[ke][cg * 16 + q * 4];
            #pragma unroll
            for (int r = 0; r < 8; ++r)
                #pragma unroll
                for (int c = 0; c < 16; ++c)
                    acc[r][c] = fmaf(a8[r], w16[c], acc[r][c]);
        }
    }

    float bh[16];
    #pragma unroll
    for (int q = 0; q < 4; ++q)
        *(float4*)&bh[q * 4] = *(const float4*)&b_h[cg * 16 + q * 4];
    #pragma unroll
    for (int r = 0; r < 8; ++r) {
        const size_t orow = (size_t)(row0 + rg * 8 + r) * HID + cg * 16;
        #pragma unroll
        for (int q = 0; q < 4; ++q) {
            float4 v;
            v.x = acc[r][q * 4 + 0] + bh[q * 4 + 0];
            v.y = acc[r][q * 4 + 1] + bh[q * 4 + 1];
            v.z = acc[r][q * 4 + 2] + bh[q * 4 + 2];
            v.w = acc[r][q * 4 + 3] + bh[q * 4 + 3];
            *reinterpret_cast<float4*>(&embW[orow + q * 4]) = v;
        }
    }
}

// ---------------------------------------------------------------------------
// Kernel B: sequential RNN — W in LDS with b128 economy (R7 k-loop) +
// R4-proven CENTRAL-COUNTER barrier (single t0 spinner per block).
// R7 lesson: per-wave flag spin = agent-scope ACQUIRE in 512 threads/iter;
//   on gfx950 the agent coherence point is beyond the per-XCD L2, so each
//   acquire invalidates cache -> invalidation storm evicted L2-resident
//   embW/W_hh (FETCH 132->348MB, 4x dispatch variance). ONE spinner/block,
//   RELAXED spin + single ACQUIRE fence after, caps it at 1/step/block.
// 256 blocks x 512 threads (147KB LDS => 1 block/CU, all co-resident).
// Block (bgrp=bid&31, jgrp=bid>>5): rows r0..r0+3, cols j0..j0+63.
// k-loop identity: wave w = k-octant; lane: cq=l&15 (4 cols), ks=l>>4
//   (16 k's). W ds_read_b128; h b128 16-lane broadcast (free multicast);
//   4-way ks-split reduced via __shfl_xor(16/32); pb [8][4][64] = 8KB.
// ---------------------------------------------------------------------------
__global__ __launch_bounds__(512, 1) void rnn_kernel(
    const int* __restrict__ inputs, const float* __restrict__ embW,
    const float* __restrict__ W_hh, float* hA, float* hB,
    int* bar)
{
    __shared__ __align__(16) float Wl[HID][COLS_PB];           // 128 KB
    __shared__ __align__(16) float hs[ROWS_PB][HID];           // 8 KB
    __shared__ __align__(16) float pb[NB_J][ROWS_PB][COLS_PB]; // 8 KB

    const int t    = threadIdx.x;
    const int w    = t >> 6;          // wave 0..7
    const int l    = t & 63;          // lane
    const int bid  = blockIdx.x;
    const int bgrp = bid & 31;
    const int jgrp = bid >> 5;
    const int j0   = jgrp * COLS_PB;
    const int r0   = bgrp * ROWS_PB;
    const int cq4  = (l & 15) * 4;    // col quad (k-loop identity)
    const int koff = w * 64 + (l >> 4) * 16;   // this thread's 16-k window
    const int rc   = t >> 6;          // combine row (valid for t<256)

    // ---- stage W slice once: wave w covers k rows w*64..w*64+63 ----
    {
        const int ksub = l >> 4;
        #pragma unroll
        for (int i = 0; i < 16; ++i) {
            const int k = w * 64 + ksub * 16 + i;
            *(float4*)&Wl[k][cq4] =
                *(const float4*)&W_hh[(size_t)k * HID + j0 + cq4];
        }
    }

    for (int ts = 0; ts < MAXLEN; ++ts) {
        float* hc = (ts & 1) ? hB : hA;
        float* hn = (ts & 1) ? hA : hB;

        // ---- stage this bgrp's h rows (relaxed agent loads, coalesced) ----
        // (previous step's barrier guarantees all sibling pieces published)
        #pragma unroll
        for (int r = 0; r < ROWS_PB; ++r) {
            const float v = __hip_atomic_load(
                &hc[(size_t)(r0 + r) * HID + w * 64 + l],
                __ATOMIC_RELAXED, __HIP_MEMORY_SCOPE_AGENT);
            hs[r][w * 64 + l] = v;
        }

        // feedforward gather (combine threads; L3 latency hides under kloop)
        float ev = 0.f;
        if (t < 256) {
            const int tok = inputs[(r0 + rc) * MAXLEN + ts];
            ev = embW[(size_t)tok * HID + j0 + l];
        }
        __syncthreads();

        // ---- k-loop: 16 k's, 4 cols, 4 rows; W b128, h b128 broadcast ----
        float acc[ROWS_PB][4];
        #pragma unroll
        for (int r = 0; r < ROWS_PB; ++r)
            #pragma unroll
            for (int c = 0; c < 4; ++c) acc[r][c] = 0.f;

        #pragma unroll
        for (int i = 0; i < 4; ++i) {
            const int kk = koff + i * 4;
            const float4 w0 = *(const float4*)&Wl[kk + 0][cq4];
            const float4 w1 = *(const float4*)&Wl[kk + 1][cq4];
            const float4 w2 = *(const float4*)&Wl[kk + 2][cq4];
            const float4 w3 = *(const float4*)&Wl[kk + 3][cq4];
            #pragma unroll
            for (int r = 0; r < ROWS_PB; ++r) {
                const float4 h4 = *(const float4*)&hs[r][kk];
                acc[r][0] = fmaf(w0.x, h4.x, acc[r][0]);
                acc[r][1] = fmaf(w0.y, h4.x, acc[r][1]);
                acc[r][2] = fmaf(w0.z, h4.x, acc[r][2]);
                acc[r][3] = fmaf(w0.w, h4.x, acc[r][3]);
                acc[r][0] = fmaf(w1.x, h4.y, acc[r][0]);
                acc[r][1] = fmaf(w1.y, h4.y, acc[r][1]);
                acc[r][2] = fmaf(w1.z, h4.y, acc[r][2]);
                acc[r][3] = fmaf(w1.w, h4.y, acc[r][3]);
                acc[r][0] = fmaf(w2.x, h4.z, acc[r][0]);
                acc[r][1] = fmaf(w2.y, h4.z, acc[r][1]);
                acc[r][2] = fmaf(w2.z, h4.z, acc[r][2]);
                acc[r][3] = fmaf(w2.w, h4.z, acc[r][3]);
                acc[r][0] = fmaf(w3.x, h4.w, acc[r][0]);
                acc[r][1] = fmaf(w3.y, h4.w, acc[r][1]);
                acc[r][2] = fmaf(w3.z, h4.w, acc[r][2]);
                acc[r][3] = fmaf(w3.w, h4.w, acc[r][3]);
            }
        }

        // ---- reduce 4-way ks split (lanes l, l^16, l^32, l^48) ----
        #pragma unroll
        for (int r = 0; r < ROWS_PB; ++r)
            #pragma unroll
            for (int c = 0; c < 4; ++c) {
                float v = acc[r][c];
                v += __shfl_xor(v, 16);
                v += __shfl_xor(v, 32);
                acc[r][c] = v;
            }
        if (l < 16) {
            #pragma unroll
            for (int r = 0; r < ROWS_PB; ++r)
                *(float4*)&pb[w][r][l * 4] = make_float4(
                    acc[r][0], acc[r][1], acc[r][2], acc[r][3]);
        }
        __syncthreads();

        // ---- combine (t<256: row rc, col l), tanh, publish ----
        if (t < 256) {
            float s = ev;
            #pragma unroll
            for (int q = 0; q < NB_J; ++q) s += pb[q][rc][l];
            s = tanhf(s);
            __hip_atomic_store(&hn[(size_t)(r0 + rc) * HID + j0 + l], s,
                               __ATOMIC_RELAXED, __HIP_MEMORY_SCOPE_AGENT);
        }
        __syncthreads();   // vmcnt drain: publish stores complete

        // ---- central 8-block barrier (R4-proven; ONE spinner/block) ----
        if (t == 0) {
            int* c = &bar[bgrp * MAXLEN + ts];
            __hip_atomic_fetch_add(c, 1, __ATOMIC_ACQ_REL,
                                   __HIP_MEMORY_SCOPE_AGENT);
            while (__hip_atomic_load(c, __ATOMIC_RELAXED,
                                     __HIP_MEMORY_SCOPE_AGENT) < NB_J) {
                __builtin_amdgcn_s_sleep(1);
            }
            __builtin_amdgcn_fence(__ATOMIC_ACQUIRE, "agent");
        }
        __syncthreads();
    }
    // final h in hA (MAXLEN even)
}

// ---------------------------------------------------------------------------
// Kernel C: logits = hA @ W_out + b_out, sigmoid. Tiny.
// ---------------------------------------------------------------------------
__global__ void head_kernel(const float* __restrict__ h_final,
                            const float* __restrict__ W_out,
                            const float* __restrict__ b_out,
                            float* __restrict__ out)
{
    const int t = threadIdx.x;
    const int b = t >> 1, c = t & 1;
    float acc = b_out[c];
    for (int k = 0; k < HID; ++k)
        acc = fmaf(h_final[(size_t)b * HID + k], W_out[k * NCLASS + c], acc);
    out[t] = 1.f / (1.f + expf(-acc));
}

// ---------------------------------------------------------------------------
extern "C" void kernel_launch(void* const* d_in, const int* in_sizes, int n_in,
                              void* d_out, int out_size, void* d_ws,
                              size_t ws_size, hipStream_t stream)
{
    const int*   inputs = (const int*)  d_in[0];
    const float* emb    = (const float*)d_in[1];
    const float* W_ih   = (const float*)d_in[2];
    const float* W_hh   = (const float*)d_in[3];
    const float* b_h    = (const float*)d_in[4];
    const float* W_out  = (const float*)d_in[5];
    const float* b_out  = (const float*)d_in[6];
    float* out = (float*)d_out;

    // ws layout: embW 64 MB | hA 256 KB | hB 256 KB | bar 64 KB
    float* embW = (float*)d_ws;
    float* hA   = embW + (size_t)VOCAB * HID;
    float* hB   = hA + (size_t)BATCH * HID;
    int*   bar  = (int*)(hB + (size_t)BATCH * HID);

    // per-launch re-init (graph-capture-safe, deterministic)
    hipMemsetAsync(hA, 0, (size_t)BATCH * HID * sizeof(float), stream);
    hipMemsetAsync(bar, 0, (size_t)NB_B * MAXLEN * sizeof(int), stream);

    embw_kernel<<<VOCAB / 64, 256, 0, stream>>>(emb, W_ih, b_h, embW);
    rnn_kernel<<<NB_B * NB_J, 512, 0, stream>>>(inputs, embW, W_hh,
                                                hA, hB, bar);
    head_kernel<<<1, 256, 0, stream>>>(hA, W_out, b_out, out);
}

// Round 10
// 4052.609 us; speedup vs baseline: 3.7264x; 1.0453x over previous
//
#include <hip/hip_runtime.h>
#include <math.h>

#define VOCAB  32000
#define EMB    256
#define HID    512
#define MAXLEN 512
#define BATCH  128
#define NCLASS 2

#define NB_J    8    // column groups (64 cols each)
#define NB_B    16   // batch groups (8 rows each)  -- R4 geometry
#define ROWS_PB 8
#define COLS_PB 64

// ---------------------------------------------------------------------------
// Kernel A: embW[v][j] = b_h[j] + sum_e emb[v][e] * W_ih[e][j]
// (unchanged — ~70 us)
// ---------------------------------------------------------------------------
__global__ __launch_bounds__(256, 1) void embw_kernel(
    const float* __restrict__ emb, const float* __restrict__ W_ih,
    const float* __restrict__ b_h, float* __restrict__ embW)
{
    __shared__ __align__(16) float aT[EMB][64];
    __shared__ __align__(16) float wS[32][HID];

    const int t    = threadIdx.x;
    const int row0 = blockIdx.x * 64;

    {
        const int row   = t >> 2;
        const int elane = t & 3;
        for (int i = 0; i < 16; ++i) {
            const int e = elane * 4 + i * 16;
            const float4 v = *reinterpret_cast<const float4*>(
                &emb[(size_t)(row0 + row) * EMB + e]);
            aT[e + 0][row] = v.x;
            aT[e + 1][row] = v.y;
            aT[e + 2][row] = v.z;
            aT[e + 3][row] = v.w;
        }
    }

    const int rg = t >> 5;
    const int cg = t & 31;

    float acc[8][16];
    #pragma unroll
    for (int r = 0; r < 8; ++r)
        #pragma unroll
        for (int c = 0; c < 16; ++c) acc[r][c] = 0.f;

    for (int ec = 0; ec < 8; ++ec) {
        __syncthreads();
        {
            const int j4  = (t & 127) * 4;
            const int keb = (t >> 7);
            #pragma unroll
            for (int i = 0; i < 16; ++i) {
                const int ke = keb + i * 2;
                const float4 v = *reinterpret_cast<const float4*>(
                    &W_ih[(size_t)(ec * 32 + ke) * HID + j4]);
                *reinterpret_cast<float4*>(&wS[ke][j4]) = v;
            }
        }
        __syncthreads();

        for (int ke = 0; ke < 32; ++ke) {
            float a8[8];
            *(float4*)&a8[0] = *(const float4*)&aT[ec * 32 + ke][rg * 8];
            *(float4*)&a8[4] = *(const float4*)&aT[ec * 32 + ke][rg * 8 + 4];
            float w16[16];
            #pragma unroll
            for (int q = 0; q < 4; ++q)
                *(float4*)&w16[q * 4] =
                    *(const float4*)&wS[ke][cg * 16 + q * 4];
            #pragma unroll
            for (int r = 0; r < 8; ++r)
                #pragma unroll
                for (int c = 0; c < 16; ++c)
                    acc[r][c] = fmaf(a8[r], w16[c], acc[r][c]);
        }
    }

    float bh[16];
    #pragma unroll
    for (int q = 0; q < 4; ++q)
        *(float4*)&bh[q * 4] = *(const float4*)&b_h[cg * 16 + q * 4];
    #pragma unroll
    for (int r = 0; r < 8; ++r) {
        const size_t orow = (size_t)(row0 + rg * 8 + r) * HID + cg * 16;
        #pragma unroll
        for (int q = 0; q < 4; ++q) {
            float4 v;
            v.x = acc[r][q * 4 + 0] + bh[q * 4 + 0];
            v.y = acc[r][q * 4 + 1] + bh[q * 4 + 1];
            v.z = acc[r][q * 4 + 2] + bh[q * 4 + 2];
            v.w = acc[r][q * 4 + 3] + bh[q * 4 + 3];
            *reinterpret_cast<float4*>(&embW[orow + q * 4]) = v;
        }
    }
}

// ---------------------------------------------------------------------------
// Kernel B: sequential RNN — R4 base (geometry + exchange + barrier,
// verbatim) with ONLY the k-loop swapped for the R8-proven b128 economy.
// 128 blocks x 512 threads (155648 B LDS = R4-proven, 1 block/CU).
// Block (bgrp=bid&15, jgrp=bid>>4): rows r0..r0+7, cols j0..j0+63.
// W slice [512][64] fp32 = 128KB LDS. k-loop identity: wave w = k-octant,
//   lane: cq=l&15 (4 cols), ks=l>>4 (16 k's). W ds_read_b128; h b128
//   16-lane broadcast; 4-way ks-split reduced via __shfl_xor(16/32).
// pb reduced in TWO stages (waves 4-7 write, waves 0-3 accumulate) so
//   pb is [4][8][64] = 8KB and total LDS stays at R4's 155648.
// Exchange/barrier: R4 VERBATIM — relaxed agent loads/stores + central
//   counter, ONE t0 spinner with ACQUIRE spin loads (R7/R8 lesson: both
//   "improved" protocols lost to this; acquire-in-one-thread is stable).
// ---------------------------------------------------------------------------
__global__ __launch_bounds__(512, 1) void rnn_kernel(
    const int* __restrict__ inputs, const float* __restrict__ embW,
    const float* __restrict__ W_hh, float* hA, float* hB,
    int* bar)
{
    __shared__ __align__(16) float Wl[HID][COLS_PB];            // 128 KB
    __shared__ __align__(16) float hs[ROWS_PB][HID];            // 16 KB
    __shared__ __align__(16) float pb[4][ROWS_PB][COLS_PB];     // 8 KB

    const int t    = threadIdx.x;
    const int w    = t >> 6;          // wave 0..7 = k-octant; combine row
    const int l    = t & 63;          // lane = local col
    const int bid  = blockIdx.x;
    const int bgrp = bid & 15;
    const int jgrp = bid >> 4;
    const int j0   = jgrp * COLS_PB;
    const int r0   = bgrp * ROWS_PB;
    const int cq4  = (l & 15) * 4;               // col quad
    const int koff = w * 64 + (l >> 4) * 16;     // this thread's 16-k window

    // ---- stage W slice once: wave w covers k rows w*64..w*64+63 ----
    {
        const int ksub = l >> 4;
        #pragma unroll
        for (int i = 0; i < 16; ++i) {
            const int k = w * 64 + ksub * 16 + i;
            *(float4*)&Wl[k][cq4] =
                *(const float4*)&W_hh[(size_t)k * HID + j0 + cq4];
        }
    }

    for (int ts = 0; ts < MAXLEN; ++ts) {
        float* hc = (ts & 1) ? hB : hA;
        float* hn = (ts & 1) ? hA : hB;

        // ---- stage this bgrp's 8 h rows (relaxed agent, coalesced) ----
        #pragma unroll
        for (int r = 0; r < ROWS_PB; ++r) {
            const float v = __hip_atomic_load(
                &hc[(size_t)(r0 + r) * HID + w * 64 + l],
                __ATOMIC_RELAXED, __HIP_MEMORY_SCOPE_AGENT);
            hs[r][w * 64 + l] = v;
        }

        // feedforward gather (row = w, col = l; L3 latency hides under kloop)
        const int   tok = inputs[(r0 + w) * MAXLEN + ts];
        const float ev  = embW[(size_t)tok * HID + j0 + l];
        __syncthreads();

        // ---- k-loop: 16 k's, 4 cols, 8 rows; W b128, h b128 broadcast ----
        float acc[ROWS_PB][4];
        #pragma unroll
        for (int r = 0; r < ROWS_PB; ++r)
            #pragma unroll
            for (int c = 0; c < 4; ++c) acc[r][c] = 0.f;

        #pragma unroll
        for (int i = 0; i < 4; ++i) {
            const int kk = koff + i * 4;
            const float4 w0 = *(const float4*)&Wl[kk + 0][cq4];
            const float4 w1 = *(const float4*)&Wl[kk + 1][cq4];
            const float4 w2 = *(const float4*)&Wl[kk + 2][cq4];
            const float4 w3 = *(const float4*)&Wl[kk + 3][cq4];
            #pragma unroll
            for (int r = 0; r < ROWS_PB; ++r) {
                const float4 h4 = *(const float4*)&hs[r][kk];
                acc[r][0] = fmaf(w0.x, h4.x, acc[r][0]);
                acc[r][1] = fmaf(w0.y, h4.x, acc[r][1]);
                acc[r][2] = fmaf(w0.z, h4.x, acc[r][2]);
                acc[r][3] = fmaf(w0.w, h4.x, acc[r][3]);
                acc[r][0] = fmaf(w1.x, h4.y, acc[r][0]);
                acc[r][1] = fmaf(w1.y, h4.y, acc[r][1]);
                acc[r][2] = fmaf(w1.z, h4.y, acc[r][2]);
                acc[r][3] = fmaf(w1.w, h4.y, acc[r][3]);
                acc[r][0] = fmaf(w2.x, h4.z, acc[r][0]);
                acc[r][1] = fmaf(w2.y, h4.z, acc[r][1]);
                acc[r][2] = fmaf(w2.z, h4.z, acc[r][2]);
                acc[r][3] = fmaf(w2.w, h4.z, acc[r][3]);
                acc[r][0] = fmaf(w3.x, h4.w, acc[r][0]);
                acc[r][1] = fmaf(w3.y, h4.w, acc[r][1]);
                acc[r][2] = fmaf(w3.z, h4.w, acc[r][2]);
                acc[r][3] = fmaf(w3.w, h4.w, acc[r][3]);
            }
        }

        // ---- reduce 4-way ks split in-register (lanes l, l^16, l^32, l^48)
        #pragma unroll
        for (int r = 0; r < ROWS_PB; ++r)
            #pragma unroll
            for (int c = 0; c < 4; ++c) {
                float v = acc[r][c];
                v += __shfl_xor(v, 16);
                v += __shfl_xor(v, 32);
                acc[r][c] = v;
            }

        // ---- two-stage octant reduction through 8KB pb ----
        if (w >= 4 && l < 16) {
            #pragma unroll
            for (int r = 0; r < ROWS_PB; ++r)
                *(float4*)&pb[w - 4][r][l * 4] = make_float4(
                    acc[r][0], acc[r][1], acc[r][2], acc[r][3]);
        }
        __syncthreads();
        if (w < 4 && l < 16) {
            #pragma unroll
            for (int r = 0; r < ROWS_PB; ++r) {
                float4 p = *(const float4*)&pb[w][r][l * 4];
                p.x += acc[r][0]; p.y += acc[r][1];
                p.z += acc[r][2]; p.w += acc[r][3];
                *(float4*)&pb[w][r][l * 4] = p;
            }
        }
        __syncthreads();

        // ---- combine (row w, col l), tanh, publish ----
        {
            float s = ev;
            #pragma unroll
            for (int q = 0; q < 4; ++q) s += pb[q][w][l];
            s = tanhf(s);
            __hip_atomic_store(&hn[(size_t)(r0 + w) * HID + j0 + l], s,
                               __ATOMIC_RELAXED, __HIP_MEMORY_SCOPE_AGENT);
        }
        __syncthreads();   // vmcnt drain: publish stores complete

        // ---- central 8-block barrier (R4 VERBATIM: acquire spin, t0) ----
        if (t == 0) {
            int* c = &bar[bgrp * MAXLEN + ts];
            __hip_atomic_fetch_add(c, 1, __ATOMIC_ACQ_REL,
                                   __HIP_MEMORY_SCOPE_AGENT);
            while (__hip_atomic_load(c, __ATOMIC_ACQUIRE,
                                     __HIP_MEMORY_SCOPE_AGENT) < NB_J) {
                __builtin_amdgcn_s_sleep(1);
            }
        }
        __syncthreads();
    }
    // final h in hA (MAXLEN even)
}

// ---------------------------------------------------------------------------
// Kernel C: logits = hA @ W_out + b_out, sigmoid. Tiny.
// ---------------------------------------------------------------------------
__global__ void head_kernel(const float* __restrict__ h_final,
                            const float* __restrict__ W_out,
                            const float* __restrict__ b_out,
                            float* __restrict__ out)
{
    const int t = threadIdx.x;
    const int b = t >> 1, c = t & 1;
    float acc = b_out[c];
    for (int k = 0; k < HID; ++k)
        acc = fmaf(h_final[(size_t)b * HID + k], W_out[k * NCLASS + c], acc);
    out[t] = 1.f / (1.f + expf(-acc));
}

// ---------------------------------------------------------------------------
extern "C" void kernel_launch(void* const* d_in, const int* in_sizes, int n_in,
                              void* d_out, int out_size, void* d_ws,
                              size_t ws_size, hipStream_t stream)
{
    const int*   inputs = (const int*)  d_in[0];
    const float* emb    = (const float*)d_in[1];
    const float* W_ih   = (const float*)d_in[2];
    const float* W_hh   = (const float*)d_in[3];
    const float* b_h    = (const float*)d_in[4];
    const float* W_out  = (const float*)d_in[5];
    const float* b_out  = (const float*)d_in[6];
    float* out = (float*)d_out;

    // ws layout: embW 64 MB | hA 256 KB | hB 256 KB | bar 32 KB
    float* embW = (float*)d_ws;
    float* hA   = embW + (size_t)VOCAB * HID;
    float* hB   = hA + (size_t)BATCH * HID;
    int*   bar  = (int*)(hB + (size_t)BATCH * HID);

    // per-launch re-init (graph-capture-safe, deterministic)
    hipMemsetAsync(hA, 0, (size_t)BATCH * HID * sizeof(float), stream);
    hipMemsetAsync(bar, 0, (size_t)NB_B * MAXLEN * sizeof(int), stream);

    embw_kernel<<<VOCAB / 64, 256, 0, stream>>>(emb, W_ih, b_h, embW);
    rnn_kernel<<<NB_B * NB_J, 512, 0, stream>>>(inputs, embW, W_hh,
                                                hA, hB, bar);
    head_kernel<<<1, 256, 0, stream>>>(hA, W_out, b_out, out);
}

// Round 11
// 3558.958 us; speedup vs baseline: 4.2433x; 1.1387x over previous
//
#include <hip/hip_runtime.h>
#include <math.h>

#define VOCAB  32000
#define EMB    256
#define HID    512
#define MAXLEN 512
#define BATCH  128
#define NCLASS 2

#define NB_J    8    // column groups (64 cols each)
#define NB_B    16   // batch groups (8 rows each)
#define ROWS_PB 8
#define COLS_PB 64

#define HSP 516      // hs row stride (pad +4 dwords: rp-groups hit distinct banks)
#define PBP 68       // pb row stride (pad +4)

// ---------------------------------------------------------------------------
// Kernel A: embW[v][j] = b_h[j] + sum_e emb[v][e] * W_ih[e][j]
// (unchanged — ~70 us)
// ---------------------------------------------------------------------------
__global__ __launch_bounds__(256, 1) void embw_kernel(
    const float* __restrict__ emb, const float* __restrict__ W_ih,
    const float* __restrict__ b_h, float* __restrict__ embW)
{
    __shared__ __align__(16) float aT[EMB][64];
    __shared__ __align__(16) float wS[32][HID];

    const int t    = threadIdx.x;
    const int row0 = blockIdx.x * 64;

    {
        const int row   = t >> 2;
        const int elane = t & 3;
        for (int i = 0; i < 16; ++i) {
            const int e = elane * 4 + i * 16;
            const float4 v = *reinterpret_cast<const float4*>(
                &emb[(size_t)(row0 + row) * EMB + e]);
            aT[e + 0][row] = v.x;
            aT[e + 1][row] = v.y;
            aT[e + 2][row] = v.z;
            aT[e + 3][row] = v.w;
        }
    }

    const int rg = t >> 5;
    const int cg = t & 31;

    float acc[8][16];
    #pragma unroll
    for (int r = 0; r < 8; ++r)
        #pragma unroll
        for (int c = 0; c < 16; ++c) acc[r][c] = 0.f;

    for (int ec = 0; ec < 8; ++ec) {
        __syncthreads();
        {
            const int j4  = (t & 127) * 4;
            const int keb = (t >> 7);
            #pragma unroll
            for (int i = 0; i < 16; ++i) {
                const int ke = keb + i * 2;
                const float4 v = *reinterpret_cast<const float4*>(
                    &W_ih[(size_t)(ec * 32 + ke) * HID + j4]);
                *reinterpret_cast<float4*>(&wS[ke][j4]) = v;
            }
        }
        __syncthreads();

        for (int ke = 0; ke < 32; ++ke) {
            float a8[8];
            *(float4*)&a8[0] = *(const float4*)&aT[ec * 32 + ke][rg * 8];
            *(float4*)&a8[4] = *(const float4*)&aT[ec * 32 + ke][rg * 8 + 4];
            float w16[16];
            #pragma unroll
            for (int q = 0; q < 4; ++q)
                *(float4*)&w16[q * 4] =
                    *(const float4*)&wS[ke][cg * 16 + q * 4];
            #pragma unroll
            for (int r = 0; r < 8; ++r)
                #pragma unroll
                for (int c = 0; c < 16; ++c)
                    acc[r][c] = fmaf(a8[r], w16[c], acc[r][c]);
        }
    }

    float bh[16];
    #pragma unroll
    for (int q = 0; q < 4; ++q)
        *(float4*)&bh[q * 4] = *(const float4*)&b_h[cg * 16 + q * 4];
    #pragma unroll
    for (int r = 0; r < 8; ++r) {
        const size_t orow = (size_t)(row0 + rg * 8 + r) * HID + cg * 16;
        #pragma unroll
        for (int q = 0; q < 4; ++q) {
            float4 v;
            v.x = acc[r][q * 4 + 0] + bh[q * 4 + 0];
            v.y = acc[r][q * 4 + 1] + bh[q * 4 + 1];
            v.z = acc[r][q * 4 + 2] + bh[q * 4 + 2];
            v.w = acc[r][q * 4 + 3] + bh[q * 4 + 3];
            *reinterpret_cast<float4*>(&embW[orow + q * 4]) = v;
        }
    }
}

// ---------------------------------------------------------------------------
// Kernel B: sequential RNN — shuffle-free k-loop + R4-verbatim exchange.
// R9 lesson: __shfl_xor on CDNA = ds_bpermute (LDS pipe!) — the "in-register"
//   4-way reduce was 64 LDS ops/thread/step and made R9 SLOWER than R4.
// New k-loop: wave w owns the FULL k-octant [64w,64w+64) — no within-wave
//   k-split, no cross-lane reduce. Lane: cq4=(l&15)*4 (4 cols), rp=l>>4
//   (rows 2rp,2rp+1). W reads: 64 b128/wave (4-way lane broadcast); h reads:
//   32 b128/wave (16-lane broadcast). Octant partials combined via the
//   two-stage pb (pure LDS, no shuffles).
// hs rows padded +4 dwords (rp-groups read different rows at same k: same
//   bank without pad -> 4-way conflict; pad shifts each row 4 banks).
//   516%4==0 keeps b128 alignment. pb rows padded +4 likewise.
// 128 blocks x 512 threads; block (bgrp=bid&15, jgrp=bid>>4): rows r0..r0+7,
//   cols j0..j0+63. Exchange/barrier: R4 VERBATIM (acquire-spin central
//   counter, ONE t0 spinner — only protocol that's been fast AND stable).
// ---------------------------------------------------------------------------
__global__ __launch_bounds__(512, 1) void rnn_kernel(
    const int* __restrict__ inputs, const float* __restrict__ embW,
    const float* __restrict__ W_hh, float* hA, float* hB,
    int* bar)
{
    __shared__ __align__(16) float Wl[HID][COLS_PB];        // 128 KB
    __shared__ __align__(16) float hs[ROWS_PB * HSP];       // 16.1 KB
    __shared__ __align__(16) float pb[4 * ROWS_PB * PBP];   // 8.5 KB

    const int t    = threadIdx.x;
    const int w    = t >> 6;          // wave 0..7 = k-octant; combine row
    const int l    = t & 63;          // lane
    const int bid  = blockIdx.x;
    const int bgrp = bid & 15;
    const int jgrp = bid >> 4;
    const int j0   = jgrp * COLS_PB;
    const int r0   = bgrp * ROWS_PB;
    const int cq4  = (l & 15) * 4;    // col quad
    const int rp   = l >> 4;          // row pair: rows 2rp, 2rp+1

    // ---- stage W slice once: wave w covers k rows w*64..w*64+63 ----
    {
        const int ksub = l >> 4;
        #pragma unroll
        for (int i = 0; i < 16; ++i) {
            const int k = w * 64 + ksub * 16 + i;
            *(float4*)&Wl[k][cq4] =
                *(const float4*)&W_hh[(size_t)k * HID + j0 + cq4];
        }
    }

    for (int ts = 0; ts < MAXLEN; ++ts) {
        float* hc = (ts & 1) ? hB : hA;
        float* hn = (ts & 1) ? hA : hB;

        // ---- stage this bgrp's 8 h rows (relaxed agent, coalesced) ----
        #pragma unroll
        for (int r = 0; r < ROWS_PB; ++r) {
            const float v = __hip_atomic_load(
                &hc[(size_t)(r0 + r) * HID + w * 64 + l],
                __ATOMIC_RELAXED, __HIP_MEMORY_SCOPE_AGENT);
            hs[r * HSP + w * 64 + l] = v;
        }

        // feedforward gather (row = w, col = l; hides under k-loop)
        const int   tok = inputs[(r0 + w) * MAXLEN + ts];
        const float ev  = embW[(size_t)tok * HID + j0 + l];
        __syncthreads();

        // ---- k-loop: full octant, 4 cols, 2 rows; NO cross-lane ops ----
        float acc0[4] = {0.f, 0.f, 0.f, 0.f};   // row 2rp
        float acc1[4] = {0.f, 0.f, 0.f, 0.f};   // row 2rp+1
        const int kb = w * 64;
        #pragma unroll 4
        for (int i = 0; i < 16; ++i) {
            const int kk = kb + i * 4;
            const float4 w0 = *(const float4*)&Wl[kk + 0][cq4];
            const float4 w1 = *(const float4*)&Wl[kk + 1][cq4];
            const float4 w2 = *(const float4*)&Wl[kk + 2][cq4];
            const float4 w3 = *(const float4*)&Wl[kk + 3][cq4];
            const float4 ha = *(const float4*)&hs[(2 * rp) * HSP + kk];
            const float4 hb = *(const float4*)&hs[(2 * rp + 1) * HSP + kk];
            acc0[0] = fmaf(w0.x, ha.x, acc0[0]);
            acc0[1] = fmaf(w0.y, ha.x, acc0[1]);
            acc0[2] = fmaf(w0.z, ha.x, acc0[2]);
            acc0[3] = fmaf(w0.w, ha.x, acc0[3]);
            acc1[0] = fmaf(w0.x, hb.x, acc1[0]);
            acc1[1] = fmaf(w0.y, hb.x, acc1[1]);
            acc1[2] = fmaf(w0.z, hb.x, acc1[2]);
            acc1[3] = fmaf(w0.w, hb.x, acc1[3]);
            acc0[0] = fmaf(w1.x, ha.y, acc0[0]);
            acc0[1] = fmaf(w1.y, ha.y, acc0[1]);
            acc0[2] = fmaf(w1.z, ha.y, acc0[2]);
            acc0[3] = fmaf(w1.w, ha.y, acc0[3]);
            acc1[0] = fmaf(w1.x, hb.y, acc1[0]);
            acc1[1] = fmaf(w1.y, hb.y, acc1[1]);
            acc1[2] = fmaf(w1.z, hb.y, acc1[2]);
            acc1[3] = fmaf(w1.w, hb.y, acc1[3]);
            acc0[0] = fmaf(w2.x, ha.z, acc0[0]);
            acc0[1] = fmaf(w2.y, ha.z, acc0[1]);
            acc0[2] = fmaf(w2.z, ha.z, acc0[2]);
            acc0[3] = fmaf(w2.w, ha.z, acc0[3]);
            acc1[0] = fmaf(w2.x, hb.z, acc1[0]);
            acc1[1] = fmaf(w2.y, hb.z, acc1[1]);
            acc1[2] = fmaf(w2.z, hb.z, acc1[2]);
            acc1[3] = fmaf(w2.w, hb.z, acc1[3]);
            acc0[0] = fmaf(w3.x, ha.w, acc0[0]);
            acc0[1] = fmaf(w3.y, ha.w, acc0[1]);
            acc0[2] = fmaf(w3.z, ha.w, acc0[2]);
            acc0[3] = fmaf(w3.w, ha.w, acc0[3]);
            acc1[0] = fmaf(w3.x, hb.w, acc1[0]);
            acc1[1] = fmaf(w3.y, hb.w, acc1[1]);
            acc1[2] = fmaf(w3.z, hb.w, acc1[2]);
            acc1[3] = fmaf(w3.w, hb.w, acc1[3]);
        }

        // ---- two-stage octant reduction through pb (no shuffles) ----
        if (w >= 4) {
            float* p = &pb[((w - 4) * ROWS_PB + 2 * rp) * PBP + cq4];
            *(float4*)p = make_float4(acc0[0], acc0[1], acc0[2], acc0[3]);
            *(float4*)(p + PBP) =
                make_float4(acc1[0], acc1[1], acc1[2], acc1[3]);
        }
        __syncthreads();
        if (w < 4) {
            float* p = &pb[(w * ROWS_PB + 2 * rp) * PBP + cq4];
            float4 p0 = *(const float4*)p;
            float4 p1 = *(const float4*)(p + PBP);
            p0.x += acc0[0]; p0.y += acc0[1];
            p0.z += acc0[2]; p0.w += acc0[3];
            p1.x += acc1[0]; p1.y += acc1[1];
            p1.z += acc1[2]; p1.w += acc1[3];
            *(float4*)p = p0;
            *(float4*)(p + PBP) = p1;
        }
        __syncthreads();

        // ---- combine (row w, col l), tanh, publish ----
        {
            float s = ev;
            #pragma unroll
            for (int q = 0; q < 4; ++q)
                s += pb[(q * ROWS_PB + w) * PBP + l];
            s = tanhf(s);
            __hip_atomic_store(&hn[(size_t)(r0 + w) * HID + j0 + l], s,
                               __ATOMIC_RELAXED, __HIP_MEMORY_SCOPE_AGENT);
        }
        __syncthreads();   // vmcnt drain: publish stores complete

        // ---- central 8-block barrier (R4 VERBATIM: acquire spin, t0) ----
        if (t == 0) {
            int* c = &bar[bgrp * MAXLEN + ts];
            __hip_atomic_fetch_add(c, 1, __ATOMIC_ACQ_REL,
                                   __HIP_MEMORY_SCOPE_AGENT);
            while (__hip_atomic_load(c, __ATOMIC_ACQUIRE,
                                     __HIP_MEMORY_SCOPE_AGENT) < NB_J) {
                __builtin_amdgcn_s_sleep(1);
            }
        }
        __syncthreads();
    }
    // final h in hA (MAXLEN even)
}

// ---------------------------------------------------------------------------
// Kernel C: logits = hA @ W_out + b_out, sigmoid. Tiny.
// ---------------------------------------------------------------------------
__global__ void head_kernel(const float* __restrict__ h_final,
                            const float* __restrict__ W_out,
                            const float* __restrict__ b_out,
                            float* __restrict__ out)
{
    const int t = threadIdx.x;
    const int b = t >> 1, c = t & 1;
    float acc = b_out[c];
    for (int k = 0; k < HID; ++k)
        acc = fmaf(h_final[(size_t)b * HID + k], W_out[k * NCLASS + c], acc);
    out[t] = 1.f / (1.f + expf(-acc));
}

// ---------------------------------------------------------------------------
extern "C" void kernel_launch(void* const* d_in, const int* in_sizes, int n_in,
                              void* d_out, int out_size, void* d_ws,
                              size_t ws_size, hipStream_t stream)
{
    const int*   inputs = (const int*)  d_in[0];
    const float* emb    = (const float*)d_in[1];
    const float* W_ih   = (const float*)d_in[2];
    const float* W_hh   = (const float*)d_in[3];
    const float* b_h    = (const float*)d_in[4];
    const float* W_out  = (const float*)d_in[5];
    const float* b_out  = (const float*)d_in[6];
    float* out = (float*)d_out;

    // ws layout: embW 64 MB | hA 256 KB | hB 256 KB | bar 32 KB
    float* embW = (float*)d_ws;
    float* hA   = embW + (size_t)VOCAB * HID;
    float* hB   = hA + (size_t)BATCH * HID;
    int*   bar  = (int*)(hB + (size_t)BATCH * HID);

    // per-launch re-init (graph-capture-safe, deterministic)
    hipMemsetAsync(hA, 0, (size_t)BATCH * HID * sizeof(float), stream);
    hipMemsetAsync(bar, 0, (size_t)NB_B * MAXLEN * sizeof(int), stream);

    embw_kernel<<<VOCAB / 64, 256, 0, stream>>>(emb, W_ih, b_h, embW);
    rnn_kernel<<<NB_B * NB_J, 512, 0, stream>>>(inputs, embW, W_hh,
                                                hA, hB, bar);
    head_kernel<<<1, 256, 0, stream>>>(hA, W_out, b_out, out);
}

// Round 12
// 1918.950 us; speedup vs baseline: 7.8698x; 1.8546x over previous
//
#include <hip/hip_runtime.h>
#include <math.h>

#define VOCAB  32000
#define EMB    256
#define HID    512
#define MAXLEN 512
#define BATCH  128
#define NCLASS 2

#define NBG 8     // batch groups (16 rows each)
#define NJG 4     // col groups (128 cols each)
#define RPB 16    // rows per block
#define CPB 128   // cols per block
#define KP  520   // padded k stride (bf16 elems) for Wb/hsb rows

typedef __attribute__((ext_vector_type(8))) short bf16x8;
typedef __attribute__((ext_vector_type(4))) float f32x4;

// round-to-nearest-even fp32 -> bf16 (bit form)
__device__ __forceinline__ unsigned short f2b_bits(unsigned int u) {
    return (unsigned short)((u + 0x7fffu + ((u >> 16) & 1u)) >> 16);
}

// ---------------------------------------------------------------------------
// Kernel A: embW[v][j] = b_h[j] + sum_e emb[v][e] * W_ih[e][j]  (fp32, exact)
// (unchanged — ~70 us)
// ---------------------------------------------------------------------------
__global__ __launch_bounds__(256, 1) void embw_kernel(
    const float* __restrict__ emb, const float* __restrict__ W_ih,
    const float* __restrict__ b_h, float* __restrict__ embW)
{
    __shared__ __align__(16) float aT[EMB][64];
    __shared__ __align__(16) float wS[32][HID];

    const int t    = threadIdx.x;
    const int row0 = blockIdx.x * 64;

    {
        const int row   = t >> 2;
        const int elane = t & 3;
        for (int i = 0; i < 16; ++i) {
            const int e = elane * 4 + i * 16;
            const float4 v = *reinterpret_cast<const float4*>(
                &emb[(size_t)(row0 + row) * EMB + e]);
            aT[e + 0][row] = v.x;
            aT[e + 1][row] = v.y;
            aT[e + 2][row] = v.z;
            aT[e + 3][row] = v.w;
        }
    }

    const int rg = t >> 5;
    const int cg = t & 31;

    float acc[8][16];
    #pragma unroll
    for (int r = 0; r < 8; ++r)
        #pragma unroll
        for (int c = 0; c < 16; ++c) acc[r][c] = 0.f;

    for (int ec = 0; ec < 8; ++ec) {
        __syncthreads();
        {
            const int j4  = (t & 127) * 4;
            const int keb = (t >> 7);
            #pragma unroll
            for (int i = 0; i < 16; ++i) {
                const int ke = keb + i * 2;
                const float4 v = *reinterpret_cast<const float4*>(
                    &W_ih[(size_t)(ec * 32 + ke) * HID + j4]);
                *reinterpret_cast<float4*>(&wS[ke][j4]) = v;
            }
        }
        __syncthreads();

        for (int ke = 0; ke < 32; ++ke) {
            float a8[8];
            *(float4*)&a8[0] = *(const float4*)&aT[ec * 32 + ke][rg * 8];
            *(float4*)&a8[4] = *(const float4*)&aT[ec * 32 + ke][rg * 8 + 4];
            float w16[16];
            #pragma unroll
            for (int q = 0; q < 4; ++q)
                *(float4*)&w16[q * 4] =
                    *(const float4*)&wS[ke][cg * 16 + q * 4];
            #pragma unroll
            for (int r = 0; r < 8; ++r)
                #pragma unroll
                for (int c = 0; c < 16; ++c)
                    acc[r][c] = fmaf(a8[r], w16[c], acc[r][c]);
        }
    }

    float bh[16];
    #pragma unroll
    for (int q = 0; q < 4; ++q)
        *(float4*)&bh[q * 4] = *(const float4*)&b_h[cg * 16 + q * 4];
    #pragma unroll
    for (int r = 0; r < 8; ++r) {
        const size_t orow = (size_t)(row0 + rg * 8 + r) * HID + cg * 16;
        #pragma unroll
        for (int q = 0; q < 4; ++q) {
            float4 v;
            v.x = acc[r][q * 4 + 0] + bh[q * 4 + 0];
            v.y = acc[r][q * 4 + 1] + bh[q * 4 + 1];
            v.z = acc[r][q * 4 + 2] + bh[q * 4 + 2];
            v.w = acc[r][q * 4 + 3] + bh[q * 4 + 3];
            *reinterpret_cast<float4*>(&embW[orow + q * 4]) = v;
        }
    }
}

// ---------------------------------------------------------------------------
// Kernel B: sequential RNN — bf16 MFMA per step (h @ W_hh), fp32 accum +
// fp32 feedforward (embW) + fp32 h exchange.
// 32 blocks x 512 threads: block (bgrp=bid&7, jgrp=bid>>3) owns 16 batch
//   rows x 128 cols. Siblings (same bgrp) = bids b, b+8, b+16, b+24 ->
//   same XCD under round-robin (perf-only).
// W slice bf16 in LDS, layout [col][KP=520] (pad -> 2-way banks, free).
//   Per step each wave reads its 16-col B-panel as 16 ds_read_b128 =
//   exactly the 1KB/instr LDS instruction floor (no broadcast waste —
//   R10 lesson: broadcast-wasteful b128 reads cost 3.8us/step).
// h staged fp32->bf16 into hsb [row][KP] in A-frag-ready layout.
// MFMA 16x16x32: A lane: row=l&15, k=(l>>4)*8+j; B lane: col=l&15, same k;
//   D lane: row=(l>>4)*4+i, col=l&15 (guide §3, m89-verified).
// Exchange/barrier: R4-VERBATIM protocol (relaxed agent atomics, central
//   counter, ONE t0 acquire-spinner) with fan-in 4 (was 8).
// ---------------------------------------------------------------------------
__global__ __launch_bounds__(512, 1) void rnn_kernel(
    const int* __restrict__ inputs, const float* __restrict__ embW,
    const float* __restrict__ W_hh, float* hA, float* hB,
    int* bar)
{
    __shared__ __align__(16) unsigned short Wb[CPB][KP];   // 133,120 B
    __shared__ __align__(16) unsigned short hsb[RPB][KP];  // 16,640 B

    const int t    = threadIdx.x;
    const int w    = t >> 6;          // wave 0..7 = col-tile
    const int l    = t & 63;
    const int lm   = l & 15;          // MFMA row/col lane index
    const int lk   = l >> 4;          // MFMA k-group / D row group
    const int bid  = blockIdx.x;
    const int bgrp = bid & 7;
    const int jgrp = bid >> 3;
    const int j0   = jgrp * CPB;
    const int r0   = bgrp * RPB;

    // ---- one-time: stage W slice to bf16 LDS [col][k] ----
    {
        const int c  = t & 127;       // local col
        const int kq = t >> 7;        // k quarter
        for (int i = 0; i < 128; i += 4) {
            const int k = kq * 128 + i;
            unsigned int u0 = __builtin_bit_cast(unsigned int,
                                W_hh[(size_t)(k + 0) * HID + j0 + c]);
            unsigned int u1 = __builtin_bit_cast(unsigned int,
                                W_hh[(size_t)(k + 1) * HID + j0 + c]);
            unsigned int u2 = __builtin_bit_cast(unsigned int,
                                W_hh[(size_t)(k + 2) * HID + j0 + c]);
            unsigned int u3 = __builtin_bit_cast(unsigned int,
                                W_hh[(size_t)(k + 3) * HID + j0 + c]);
            unsigned int p0 = (unsigned int)f2b_bits(u0) |
                              ((unsigned int)f2b_bits(u1) << 16);
            unsigned int p1 = (unsigned int)f2b_bits(u2) |
                              ((unsigned int)f2b_bits(u3) << 16);
            *(unsigned long long*)&Wb[c][k] =
                (unsigned long long)p0 | ((unsigned long long)p1 << 32);
        }
    }

    for (int ts = 0; ts < MAXLEN; ++ts) {
        const float* hc = (ts & 1) ? hB : hA;
        float*       hn = (ts & 1) ? hA : hB;

        // ---- stage 16 h rows: fp32 relaxed-agent loads -> bf16 LDS ----
        #pragma unroll
        for (int q = 0; q < 2; ++q) {
            const int chunk = t + q * 512;        // 0..1023
            const int row   = chunk >> 6;         // 0..15
            const int kc    = (chunk & 63) * 8;   // 0..504
            const unsigned long long* src = (const unsigned long long*)
                &hc[(size_t)(r0 + row) * HID + kc];
            unsigned long long d0 = __hip_atomic_load(src + 0,
                __ATOMIC_RELAXED, __HIP_MEMORY_SCOPE_AGENT);
            unsigned long long d1 = __hip_atomic_load(src + 1,
                __ATOMIC_RELAXED, __HIP_MEMORY_SCOPE_AGENT);
            unsigned long long d2 = __hip_atomic_load(src + 2,
                __ATOMIC_RELAXED, __HIP_MEMORY_SCOPE_AGENT);
            unsigned long long d3 = __hip_atomic_load(src + 3,
                __ATOMIC_RELAXED, __HIP_MEMORY_SCOPE_AGENT);
            unsigned int q0 = (unsigned int)f2b_bits((unsigned int)d0) |
                              ((unsigned int)f2b_bits((unsigned int)(d0 >> 32)) << 16);
            unsigned int q1 = (unsigned int)f2b_bits((unsigned int)d1) |
                              ((unsigned int)f2b_bits((unsigned int)(d1 >> 32)) << 16);
            unsigned int q2 = (unsigned int)f2b_bits((unsigned int)d2) |
                              ((unsigned int)f2b_bits((unsigned int)(d2 >> 32)) << 16);
            unsigned int q3 = (unsigned int)f2b_bits((unsigned int)d3) |
                              ((unsigned int)f2b_bits((unsigned int)(d3 >> 32)) << 16);
            *(unsigned long long*)&hsb[row][kc] =
                (unsigned long long)q0 | ((unsigned long long)q1 << 32);
            *(unsigned long long*)&hsb[row][kc + 4] =
                (unsigned long long)q2 | ((unsigned long long)q3 << 32);
        }

        // ---- feedforward gather for this lane's 4 output rows (fp32) ----
        float ev[4];
        #pragma unroll
        for (int i = 0; i < 4; ++i) {
            const int r   = lk * 4 + i;
            const int tok = inputs[(r0 + r) * MAXLEN + ts];
            ev[i] = embW[(size_t)tok * HID + j0 + w * 16 + lm];
        }
        __syncthreads();

        // ---- MFMA: col-tile w (cols j0+16w..+15), K=512 = 16 k-tiles ----
        f32x4 ae = {0.f, 0.f, 0.f, 0.f};
        f32x4 ao = {0.f, 0.f, 0.f, 0.f};
        #pragma unroll
        for (int kt = 0; kt < 16; kt += 2) {
            const bf16x8 a0 = *(const bf16x8*)&hsb[lm][kt * 32 + lk * 8];
            const bf16x8 b0 = *(const bf16x8*)&Wb[w * 16 + lm][kt * 32 + lk * 8];
            ae = __builtin_amdgcn_mfma_f32_16x16x32_bf16(a0, b0, ae, 0, 0, 0);
            const bf16x8 a1 = *(const bf16x8*)&hsb[lm][(kt + 1) * 32 + lk * 8];
            const bf16x8 b1 = *(const bf16x8*)&Wb[w * 16 + lm][(kt + 1) * 32 + lk * 8];
            ao = __builtin_amdgcn_mfma_f32_16x16x32_bf16(a1, b1, ao, 0, 0, 0);
        }
        const f32x4 cc = ae + ao;

        // ---- tanh + publish (D lane: row = lk*4+i, col = w*16+lm) ----
        #pragma unroll
        for (int i = 0; i < 4; ++i) {
            const float s = tanhf(cc[i] + ev[i]);
            __hip_atomic_store(
                &hn[(size_t)(r0 + lk * 4 + i) * HID + j0 + w * 16 + lm], s,
                __ATOMIC_RELAXED, __HIP_MEMORY_SCOPE_AGENT);
        }
        __syncthreads();   // vmcnt drain: publish stores complete

        // ---- central 4-block barrier (R4-verbatim protocol) ----
        if (t == 0) {
            int* c = &bar[bgrp * MAXLEN + ts];
            __hip_atomic_fetch_add(c, 1, __ATOMIC_ACQ_REL,
                                   __HIP_MEMORY_SCOPE_AGENT);
            while (__hip_atomic_load(c, __ATOMIC_ACQUIRE,
                                     __HIP_MEMORY_SCOPE_AGENT) < NJG) {
                __builtin_amdgcn_s_sleep(1);
            }
        }
        __syncthreads();
    }
    // final h in hA (MAXLEN even)
}

// ---------------------------------------------------------------------------
// Kernel C: logits = hA @ W_out + b_out, sigmoid. Tiny. (fp32, unchanged)
// ---------------------------------------------------------------------------
__global__ void head_kernel(const float* __restrict__ h_final,
                            const float* __restrict__ W_out,
                            const float* __restrict__ b_out,
                            float* __restrict__ out)
{
    const int t = threadIdx.x;
    const int b = t >> 1, c = t & 1;
    float acc = b_out[c];
    for (int k = 0; k < HID; ++k)
        acc = fmaf(h_final[(size_t)b * HID + k], W_out[k * NCLASS + c], acc);
    out[t] = 1.f / (1.f + expf(-acc));
}

// ---------------------------------------------------------------------------
extern "C" void kernel_launch(void* const* d_in, const int* in_sizes, int n_in,
                              void* d_out, int out_size, void* d_ws,
                              size_t ws_size, hipStream_t stream)
{
    const int*   inputs = (const int*)  d_in[0];
    const float* emb    = (const float*)d_in[1];
    const float* W_ih   = (const float*)d_in[2];
    const float* W_hh   = (const float*)d_in[3];
    const float* b_h    = (const float*)d_in[4];
    const float* W_out  = (const float*)d_in[5];
    const float* b_out  = (const float*)d_in[6];
    float* out = (float*)d_out;

    // ws layout: embW 64 MB | hA 256 KB | hB 256 KB | bar 16 KB
    float* embW = (float*)d_ws;
    float* hA   = embW + (size_t)VOCAB * HID;
    float* hB   = hA + (size_t)BATCH * HID;
    int*   bar  = (int*)(hB + (size_t)BATCH * HID);

    // per-launch re-init (graph-capture-safe, deterministic)
    hipMemsetAsync(hA, 0, (size_t)BATCH * HID * sizeof(float), stream);
    hipMemsetAsync(bar, 0, (size_t)NBG * MAXLEN * sizeof(int), stream);

    embw_kernel<<<VOCAB / 64, 256, 0, stream>>>(emb, W_ih, b_h, embW);
    rnn_kernel<<<NBG * NJG, 512, 0, stream>>>(inputs, embW, W_hh,
                                              hA, hB, bar);
    head_kernel<<<1, 256, 0, stream>>>(hA, W_out, b_out, out);
}